// Round 11
// baseline (159.209 us; speedup 1.0000x reference)
//
#include <hip/hip_runtime.h>

// ---------------------------------------------------------------------------
// GCN 2-layer: out = A_norm * relu(A_norm*(X@W1)+b1) @ W2 + b2
// A_norm = D^-1/2 (A + I) D^-1/2.
//
// Round-11: r10 fusion kept, dinv restored to hs pre-scale. Per-node degree
// is histogrammed EARLY in k_rhist (same col[] read as the bucket histogram),
// so the fused gemm1 can compute dinv = rsqrt(deg+1), pre-scale hs, and emit
// the global dinv[] array. gather1 reverts to the pure-add r9 form.
//   CSR: memset + rhist(+deg,+weight prep) + {rscatter || gemm1+dinv} + bsort
//   hs  = bf16( dinv * (X@W1) )   [n][128]   [fused gemm1, MFMA]
//   h1  = relu(dinv[c]*(sum hs[s] + hs[c]) + b1)        [gather1]
//   ps2 = bf16( dinv * (h1@W2) )  [n][64]    [gemm2, MFMA]
//   out = dinv*(A.ps2)+b2  fp32   [n][64]    [gather2]
// ---------------------------------------------------------------------------

typedef float f32x4 __attribute__((ext_vector_type(4)));
typedef short bf16x8 __attribute__((ext_vector_type(8)));

#define EPB 4096   // edges per block in bucket pass 1

__device__ inline float bf2f(unsigned short u) {
    return __uint_as_float(((unsigned int)u) << 16);
}
__device__ inline unsigned short f2bf(float f) {
    unsigned int x = __float_as_uint(f);
    x = x + 0x7FFFu + ((x >> 16) & 1u);   // round-to-nearest-even
    return (unsigned short)(x >> 16);
}
__device__ inline float4 cvt4(ushort4 u) {
    return make_float4(bf2f(u.x), bf2f(u.y), bf2f(u.z), bf2f(u.w));
}
__device__ inline void add4(float4& a, float4 v) {
    a.x += v.x; a.y += v.y; a.z += v.z; a.w += v.w;
}

// Pass 1: per-(bucket,block) offsets via atomicAdd into bucket counters,
// PLUS per-node degree histogram (global atomics, same col[] read).
// Extra blocks (>= nbR) convert/transpose weights to bf16.
__global__ __launch_bounds__(256) void k_rhist(const int* __restrict__ col,
                                               int* __restrict__ bbase,
                                               int* __restrict__ bucket_cnt,
                                               int* __restrict__ deg,
                                               const float* __restrict__ W1,
                                               const float* __restrict__ W2,
                                               unsigned short* __restrict__ Wt1,
                                               unsigned short* __restrict__ Wt2,
                                               int e, int nbR, int nbB) {
    if ((int)blockIdx.x >= nbR) {
        int i = ((int)blockIdx.x - nbR) * 256 + threadIdx.x;
        if (i < 16384) {                       // W1: 128x128
            int k = i >> 7, nc = i & 127;
            Wt1[nc * 128 + k] = f2bf(W1[i]);
        } else if (i < 24576) {                // W2: 128x64
            int i2 = i - 16384;
            int k = i2 >> 6, nc = i2 & 63;
            Wt2[nc * 128 + k] = f2bf(W2[i2]);
        }
        return;
    }
    __shared__ int h[256];
    int t = threadIdx.x;
    h[t] = 0;
    __syncthreads();
    int base = blockIdx.x * EPB;
#pragma unroll
    for (int i = 0; i < EPB / 256; ++i) {
        int idx = base + t + i * 256;
        if (idx < e) {
            int c = col[idx];
            atomicAdd(&h[c >> 8], 1);
            atomicAdd(&deg[c], 1);
        }
    }
    __syncthreads();
    if (t < nbB) bbase[t * nbR + blockIdx.x] = atomicAdd(&bucket_cnt[t], h[t]);
}

// FUSED dispatch: blocks [0,nbR) = bucket scatter; blocks [nbR,nbR+nbg) =
// gemm1 (hs = bf16(dinv*(X@W1))), computing dinv from deg and emitting it.
__global__ __launch_bounds__(256, 2) void k_fused(const int* __restrict__ row,
                                                  const int* __restrict__ col,
                                                  const int* __restrict__ bucket_cnt,
                                                  const int* __restrict__ bbase,
                                                  unsigned int* __restrict__ tmp,
                                                  const float* __restrict__ x,
                                                  const unsigned short* __restrict__ Wt,
                                                  const int* __restrict__ deg,
                                                  float* __restrict__ dinv,
                                                  unsigned short* __restrict__ hs,
                                                  int e, int n, int nbR, int nbB) {
    __shared__ int sbase[256];
    __shared__ int sh[256];
    __shared__ unsigned short Xs[128 * 136];
    __shared__ unsigned short Ws[128 * 136];
    __shared__ float dinv_s[128];
    int t = threadIdx.x;

    if ((int)blockIdx.x < nbR) {
        // ---- bucket scatter (tmp entry: (col&255)<<16 | row) ----
        int v = (t < nbB) ? bucket_cnt[t] : 0;
        sbase[t] = v;
        __syncthreads();
#pragma unroll
        for (int off = 1; off < 256; off <<= 1) {
            int u = (t >= off) ? sbase[t - off] : 0;
            __syncthreads();
            sbase[t] += u;
            __syncthreads();
        }
        int excl = sbase[t] - v;
        sbase[t] = excl + ((t < nbB) ? bbase[t * nbR + blockIdx.x] : 0);
        sh[t] = 0;
        __syncthreads();
        int b0 = blockIdx.x * EPB;
#pragma unroll
        for (int i = 0; i < EPB / 256; ++i) {
            int idx = b0 + t + i * 256;
            if (idx < e) {
                int c = col[idx];
                int bin = c >> 8;
                int rk = atomicAdd(&sh[bin], 1);
                tmp[sbase[bin] + rk] =
                    ((unsigned int)(c & 255) << 16) | (unsigned int)row[idx];
            }
        }
        return;
    }

    // ---- gemm1: tile 128x128, K=128, MFMA 16x16x32 ----
    int r0blk = ((int)blockIdx.x - nbR) * 128;

#pragma unroll
    for (int i = 0; i < 8; ++i) {
        int c = t + i * 256;
        int nc = c >> 4;
        int k0 = (c & 15) * 8;
        bf16x8 v = *(const bf16x8*)&Wt[nc * 128 + k0];
        *(bf16x8*)&Ws[nc * 136 + k0] = v;
    }
#pragma unroll
    for (int i = 0; i < 16; ++i) {
        int c = t + i * 256;
        int r = c >> 5;
        int kq = c & 31;
        float4 v = make_float4(0.f, 0.f, 0.f, 0.f);
        int gr = r0blk + r;
        if (gr < n) v = ((const float4*)x)[gr * 32 + kq];
        ushort4 o;
        o.x = f2bf(v.x); o.y = f2bf(v.y); o.z = f2bf(v.z); o.w = f2bf(v.w);
        *(ushort4*)&Xs[r * 136 + kq * 4] = o;
    }
    if (t < 128) {
        int gr = r0blk + t;
        float dv = 0.f;
        if (gr < n) {
            dv = rsqrtf((float)deg[gr] + 1.0f);
            dinv[gr] = dv;
        }
        dinv_s[t] = dv;
    }
    __syncthreads();

    int lane = t & 63, wave = t >> 6;
    int lrow = lane & 15;
    int lk = (lane >> 4) * 8;

    f32x4 acc[2][8];
#pragma unroll
    for (int mi = 0; mi < 2; ++mi)
#pragma unroll
        for (int ni = 0; ni < 8; ++ni) acc[mi][ni] = (f32x4){0.f, 0.f, 0.f, 0.f};

#pragma unroll
    for (int ks = 0; ks < 4; ++ks) {
        int kk = ks * 32 + lk;
        bf16x8 a0 = *(bf16x8*)&Xs[(wave * 32 + lrow) * 136 + kk];
        bf16x8 a1 = *(bf16x8*)&Xs[(wave * 32 + 16 + lrow) * 136 + kk];
#pragma unroll
        for (int ni = 0; ni < 8; ++ni) {
            bf16x8 b = *(bf16x8*)&Ws[(ni * 16 + lrow) * 136 + kk];
            acc[0][ni] = __builtin_amdgcn_mfma_f32_16x16x32_bf16(a0, b, acc[0][ni], 0, 0, 0);
            acc[1][ni] = __builtin_amdgcn_mfma_f32_16x16x32_bf16(a1, b, acc[1][ni], 0, 0, 0);
        }
    }

    int rq = (lane >> 4) * 4;
#pragma unroll
    for (int mi = 0; mi < 2; ++mi)
#pragma unroll
        for (int r = 0; r < 4; ++r) {
            int lrw = wave * 32 + mi * 16 + rq + r;
            int grow = r0blk + lrw;
            if (grow < n) {
                float dv = dinv_s[lrw];
#pragma unroll
                for (int ni = 0; ni < 8; ++ni)
                    hs[grow * 128 + ni * 16 + lrow] = f2bf(acc[mi][ni][r] * dv);
            }
        }
}

// Pass 2: per-bucket counting sort; emits indptr, srcidx. Bucket range
// re-derived locally from bucket_cnt. (dinv now produced by k_fused.)
__global__ __launch_bounds__(256) void k_bsort(const unsigned int* __restrict__ tmp,
                                               const int* __restrict__ bucket_cnt,
                                               int* __restrict__ indptr,
                                               unsigned short* __restrict__ srcidx,
                                               int n, int e, int nbB) {
    __shared__ int cnt[256];
    __shared__ int pre[256];
    int b = blockIdx.x;
    int t = threadIdx.x;

    int v = (t < nbB) ? bucket_cnt[t] : 0;
    pre[t] = v;
    __syncthreads();
#pragma unroll
    for (int off = 1; off < 256; off <<= 1) {
        int u = (t >= off) ? pre[t - off] : 0;
        __syncthreads();
        pre[t] += u;
        __syncthreads();
    }
    int beg = pre[b] - ((b < nbB) ? bucket_cnt[b] : 0);
    int end = pre[b];
    __syncthreads();

    cnt[t] = 0;
    __syncthreads();
    for (int i = beg + t; i < end; i += 256) atomicAdd(&cnt[tmp[i] >> 16], 1);
    __syncthreads();
    v = cnt[t];
    pre[t] = v;
    __syncthreads();
#pragma unroll
    for (int off = 1; off < 256; off <<= 1) {
        int u = (t >= off) ? pre[t - off] : 0;
        __syncthreads();
        pre[t] += u;
        __syncthreads();
    }
    int myexcl = pre[t] - v;
    int node = b * 256 + t;
    if (node < n) indptr[node] = beg + myexcl;
    if (b == nbB - 1 && t == 0) indptr[n] = e;
    __syncthreads();
    pre[t] = beg + myexcl;
    cnt[t] = 0;
    __syncthreads();
    for (int i = beg + t; i < end; i += 256) {
        unsigned int u = tmp[i];
        int cl = u >> 16;
        int rk = atomicAdd(&cnt[cl], 1);
        srcidx[pre[cl] + rk] = (unsigned short)(u & 0xFFFFu);
    }
}

// Gather1: one wave per node; contiguous half-runs, 8 gathers in flight.
// hs is pre-scaled by dinv[src]; epilogue applies dinv[col], bias, relu.
__global__ __launch_bounds__(256) void k_gather1(const int* __restrict__ indptr,
                                                 const unsigned short* __restrict__ srcidx,
                                                 const unsigned short* __restrict__ hs,
                                                 const float* __restrict__ dinv,
                                                 const float* __restrict__ b1,
                                                 unsigned short* __restrict__ h1, int n) {
    int wid = (blockIdx.x * 256 + threadIdx.x) >> 6;
    if (wid >= n) return;
    int lane = threadIdx.x & 63;
    int half = lane >> 5;
    int hl = lane & 31;
    const ushort4* hv = (const ushort4*)hs;   // row stride 32 ushort4

    int beg = indptr[wid], end = indptr[wid + 1];
    int c0 = (end - beg + 1) >> 1;
    int j    = beg + half * c0;
    int jend = half ? end : (beg + c0);

    float4 a0 = make_float4(0.f, 0.f, 0.f, 0.f), a1 = a0, a2 = a0, a3 = a0;

    for (; j + 7 < jend; j += 8) {
        int s0 = srcidx[j],     s1 = srcidx[j + 1];
        int s2 = srcidx[j + 2], s3 = srcidx[j + 3];
        int s4 = srcidx[j + 4], s5 = srcidx[j + 5];
        int s6 = srcidx[j + 6], s7 = srcidx[j + 7];
        float4 v0 = cvt4(hv[s0 * 32 + hl]);
        float4 v1 = cvt4(hv[s1 * 32 + hl]);
        float4 v2 = cvt4(hv[s2 * 32 + hl]);
        float4 v3 = cvt4(hv[s3 * 32 + hl]);
        float4 v4 = cvt4(hv[s4 * 32 + hl]);
        float4 v5 = cvt4(hv[s5 * 32 + hl]);
        float4 v6 = cvt4(hv[s6 * 32 + hl]);
        float4 v7 = cvt4(hv[s7 * 32 + hl]);
        add4(a0, v0); add4(a1, v1); add4(a2, v2); add4(a3, v3);
        add4(a0, v4); add4(a1, v5); add4(a2, v6); add4(a3, v7);
    }
    if (j + 3 < jend) {
        int s0 = srcidx[j], s1 = srcidx[j + 1], s2 = srcidx[j + 2], s3 = srcidx[j + 3];
        add4(a0, cvt4(hv[s0 * 32 + hl]));
        add4(a1, cvt4(hv[s1 * 32 + hl]));
        add4(a2, cvt4(hv[s2 * 32 + hl]));
        add4(a3, cvt4(hv[s3 * 32 + hl]));
        j += 4;
    }
    for (; j < jend; ++j) add4(a0, cvt4(hv[srcidx[j] * 32 + hl]));

    if (half == 0) add4(a1, cvt4(hv[wid * 32 + hl]));   // self-loop once

    float4 tsum;
    tsum.x = a0.x + a1.x + a2.x + a3.x;
    tsum.y = a0.y + a1.y + a2.y + a3.y;
    tsum.z = a0.z + a1.z + a2.z + a3.z;
    tsum.w = a0.w + a1.w + a2.w + a3.w;
    tsum.x += __shfl_xor(tsum.x, 32);
    tsum.y += __shfl_xor(tsum.y, 32);
    tsum.z += __shfl_xor(tsum.z, 32);
    tsum.w += __shfl_xor(tsum.w, 32);

    if (half == 0) {
        float d = dinv[wid];
        float4 bb = *(const float4*)&b1[hl * 4];
        ushort4 o;
        o.x = f2bf(fmaxf(tsum.x * d + bb.x, 0.f));
        o.y = f2bf(fmaxf(tsum.y * d + bb.y, 0.f));
        o.z = f2bf(fmaxf(tsum.z * d + bb.z, 0.f));
        o.w = f2bf(fmaxf(tsum.w * d + bb.w, 0.f));
        ((ushort4*)h1)[wid * 32 + hl] = o;
    }
}

// GEMM2 (MFMA): ps2 = bf16( dinv[i] * (h1 @ W2) ). Tile 128x64, K=128.
__global__ __launch_bounds__(256, 3) void k_gemm2(const unsigned short* __restrict__ h1,
                                                  const unsigned short* __restrict__ Wt,
                                                  const float* __restrict__ dinv,
                                                  unsigned short* __restrict__ ps2, int n) {
    __shared__ unsigned short Xs[128 * 136];
    __shared__ unsigned short Ws[64 * 136];
    __shared__ float dinv_s[128];
    int t = threadIdx.x;
    int r0blk = blockIdx.x * 128;

#pragma unroll
    for (int i = 0; i < 4; ++i) {
        int c = t + i * 256;
        int nc = c >> 4;
        int k0 = (c & 15) * 8;
        bf16x8 v = *(const bf16x8*)&Wt[nc * 128 + k0];
        *(bf16x8*)&Ws[nc * 136 + k0] = v;
    }
#pragma unroll
    for (int i = 0; i < 8; ++i) {
        int c = t + i * 256;
        int r = c >> 4;
        int k0 = (c & 15) * 8;
        int gr = r0blk + r;
        bf16x8 v = (bf16x8)(short)0;
        if (gr < n) v = *(const bf16x8*)&h1[gr * 128 + k0];
        *(bf16x8*)&Xs[r * 136 + k0] = v;
    }
    if (t < 128) {
        int gr = r0blk + t;
        dinv_s[t] = (gr < n) ? dinv[gr] : 0.f;
    }
    __syncthreads();

    int lane = t & 63, wave = t >> 6;
    int lrow = lane & 15;
    int lk = (lane >> 4) * 8;

    f32x4 acc[2][4];
#pragma unroll
    for (int mi = 0; mi < 2; ++mi)
#pragma unroll
        for (int ni = 0; ni < 4; ++ni) acc[mi][ni] = (f32x4){0.f, 0.f, 0.f, 0.f};

#pragma unroll
    for (int ks = 0; ks < 4; ++ks) {
        int kk = ks * 32 + lk;
        bf16x8 a0 = *(bf16x8*)&Xs[(wave * 32 + lrow) * 136 + kk];
        bf16x8 a1 = *(bf16x8*)&Xs[(wave * 32 + 16 + lrow) * 136 + kk];
#pragma unroll
        for (int ni = 0; ni < 4; ++ni) {
            bf16x8 b = *(bf16x8*)&Ws[(ni * 16 + lrow) * 136 + kk];
            acc[0][ni] = __builtin_amdgcn_mfma_f32_16x16x32_bf16(a0, b, acc[0][ni], 0, 0, 0);
            acc[1][ni] = __builtin_amdgcn_mfma_f32_16x16x32_bf16(a1, b, acc[1][ni], 0, 0, 0);
        }
    }

    int rq = (lane >> 4) * 4;
#pragma unroll
    for (int mi = 0; mi < 2; ++mi)
#pragma unroll
        for (int r = 0; r < 4; ++r) {
            int lrw = wave * 32 + mi * 16 + rq + r;
            int grow = r0blk + lrw;
            if (grow < n) {
                float dv = dinv_s[lrw];
#pragma unroll
                for (int ni = 0; ni < 4; ++ni)
                    ps2[grow * 64 + ni * 16 + lrow] = f2bf(acc[mi][ni][r] * dv);
            }
        }
}

// Gather2: one wave per node; contiguous half-runs, 8 in flight, uint/lane.
__global__ __launch_bounds__(256) void k_gather2(const int* __restrict__ indptr,
                                                 const unsigned short* __restrict__ srcidx,
                                                 const unsigned short* __restrict__ ps2,
                                                 const float* __restrict__ dinv,
                                                 const float* __restrict__ b2,
                                                 float* __restrict__ out, int n) {
    int wid = (blockIdx.x * 256 + threadIdx.x) >> 6;
    if (wid >= n) return;
    int lane = threadIdx.x & 63;
    int half = lane >> 5;
    int hl = lane & 31;
    const unsigned int* pv = (const unsigned int*)ps2;   // row stride 32 uints

    int beg = indptr[wid], end = indptr[wid + 1];
    int c0 = (end - beg + 1) >> 1;
    int j    = beg + half * c0;
    int jend = half ? end : (beg + c0);

    float2 a0 = make_float2(0.f, 0.f), a1 = a0, a2 = a0, a3 = a0;

    for (; j + 7 < jend; j += 8) {
        int s0 = srcidx[j],     s1 = srcidx[j + 1];
        int s2 = srcidx[j + 2], s3 = srcidx[j + 3];
        int s4 = srcidx[j + 4], s5 = srcidx[j + 5];
        int s6 = srcidx[j + 6], s7 = srcidx[j + 7];
        unsigned int u0 = pv[s0 * 32 + hl];
        unsigned int u1 = pv[s1 * 32 + hl];
        unsigned int u2 = pv[s2 * 32 + hl];
        unsigned int u3 = pv[s3 * 32 + hl];
        unsigned int u4 = pv[s4 * 32 + hl];
        unsigned int u5 = pv[s5 * 32 + hl];
        unsigned int u6 = pv[s6 * 32 + hl];
        unsigned int u7 = pv[s7 * 32 + hl];
        a0.x += bf2f((unsigned short)u0); a0.y += bf2f((unsigned short)(u0 >> 16));
        a1.x += bf2f((unsigned short)u1); a1.y += bf2f((unsigned short)(u1 >> 16));
        a2.x += bf2f((unsigned short)u2); a2.y += bf2f((unsigned short)(u2 >> 16));
        a3.x += bf2f((unsigned short)u3); a3.y += bf2f((unsigned short)(u3 >> 16));
        a0.x += bf2f((unsigned short)u4); a0.y += bf2f((unsigned short)(u4 >> 16));
        a1.x += bf2f((unsigned short)u5); a1.y += bf2f((unsigned short)(u5 >> 16));
        a2.x += bf2f((unsigned short)u6); a2.y += bf2f((unsigned short)(u6 >> 16));
        a3.x += bf2f((unsigned short)u7); a3.y += bf2f((unsigned short)(u7 >> 16));
    }
    if (j + 3 < jend) {
        int s0 = srcidx[j], s1 = srcidx[j + 1], s2 = srcidx[j + 2], s3 = srcidx[j + 3];
        unsigned int u0 = pv[s0 * 32 + hl];
        unsigned int u1 = pv[s1 * 32 + hl];
        unsigned int u2 = pv[s2 * 32 + hl];
        unsigned int u3 = pv[s3 * 32 + hl];
        a0.x += bf2f((unsigned short)u0); a0.y += bf2f((unsigned short)(u0 >> 16));
        a1.x += bf2f((unsigned short)u1); a1.y += bf2f((unsigned short)(u1 >> 16));
        a2.x += bf2f((unsigned short)u2); a2.y += bf2f((unsigned short)(u2 >> 16));
        a3.x += bf2f((unsigned short)u3); a3.y += bf2f((unsigned short)(u3 >> 16));
        j += 4;
    }
    for (; j < jend; ++j) {
        unsigned int u = pv[srcidx[j] * 32 + hl];
        a0.x += bf2f((unsigned short)u); a0.y += bf2f((unsigned short)(u >> 16));
    }

    if (half == 0) {   // self-loop once
        unsigned int u = pv[wid * 32 + hl];
        a1.x += bf2f((unsigned short)u); a1.y += bf2f((unsigned short)(u >> 16));
    }

    float2 tsum;
    tsum.x = a0.x + a1.x + a2.x + a3.x;
    tsum.y = a0.y + a1.y + a2.y + a3.y;
    tsum.x += __shfl_xor(tsum.x, 32);
    tsum.y += __shfl_xor(tsum.y, 32);

    if (half == 0) {
        float d = dinv[wid];
        float2 bb = *(const float2*)&b2[hl * 2];
        float2 o;
        o.x = tsum.x * d + bb.x;
        o.y = tsum.y * d + bb.y;
        ((float2*)out)[wid * 32 + hl] = o;
    }
}

extern "C" void kernel_launch(void* const* d_in, const int* in_sizes, int n_in,
                              void* d_out, int out_size, void* d_ws, size_t ws_size,
                              hipStream_t stream) {
    const float* x  = (const float*)d_in[0];
    const int*   ei = (const int*)d_in[1];
    const float* W1 = (const float*)d_in[2];
    const float* b1 = (const float*)d_in[3];
    const float* W2 = (const float*)d_in[4];
    const float* b2 = (const float*)d_in[5];
    float* out = (float*)d_out;

    int n = in_sizes[0] / 128;       // 50000
    int e = in_sizes[1] / 2;         // 800000
    const int* row = ei;             // sources
    const int* col = ei + e;         // destinations

    int nbR = (e + EPB - 1) / EPB;   // 196 pass-1 blocks
    int nbB = (n + 255) / 256;       // 196 buckets
    int m   = nbB * nbR;             // 38416 per-(bucket,block) offsets
    int nbg = (n + 127) / 128;       // 391 gemm blocks

    // Workspace layout (int units; 16B-aligned sections).
    // bucket_cnt and deg are contiguous -> one memset covers both.
    int* iw = (int*)d_ws;
    size_t o = 0;
    int* bucket_cnt  = iw + o; o += 256;
    int* deg         = iw + o; o += (size_t)n;           o = (o + 3) & ~(size_t)3;
    int* bbase       = iw + o; o += (size_t)m;           o = (o + 3) & ~(size_t)3;
    int* indptr      = iw + o; o += (size_t)(n + 1);     o = (o + 3) & ~(size_t)3;
    float* dinv      = (float*)(iw + o); o += (size_t)n; o = (o + 3) & ~(size_t)3;
    unsigned int* tmp = (unsigned int*)(iw + o); o += (size_t)e; o = (o + 3) & ~(size_t)3;
    unsigned short* srcidx = (unsigned short*)(iw + o); o += (size_t)(e / 2 + 2); o = (o + 3) & ~(size_t)3;
    unsigned short* Wt1 = (unsigned short*)(iw + o); o += 8192;
    unsigned short* Wt2 = (unsigned short*)(iw + o); o += 4096;
    unsigned short* hs  = (unsigned short*)(iw + o);     // [n][128] bf16 (pre-scaled)
    unsigned short* h1  = hs + (size_t)n * 128;          // [n][128] bf16
    unsigned short* ps2 = hs;                            // reuse: [n][64]

    hipMemsetAsync(bucket_cnt, 0, (256 + (size_t)n) * sizeof(int), stream);
    k_rhist<<<nbR + 96, 256, 0, stream>>>(col, bbase, bucket_cnt, deg, W1, W2, Wt1, Wt2, e, nbR, nbB);
    k_fused<<<nbR + nbg, 256, 0, stream>>>(row, col, bucket_cnt, bbase, tmp, x, Wt1, deg, dinv, hs, e, n, nbR, nbB);
    k_bsort<<<nbB, 256, 0, stream>>>(tmp, bucket_cnt, indptr, srcidx, n, e, nbB);

    k_gather1<<<(n * 64 + 255) / 256, 256, 0, stream>>>(indptr, srcidx, hs, dinv, b1, h1, n);
    k_gemm2<<<nbg, 256, 0, stream>>>(h1, Wt2, dinv, ps2, n);
    k_gather2<<<(n * 64 + 255) / 256, 256, 0, stream>>>(indptr, srcidx, ps2, dinv, b2, out, n);
}

// Round 12
// 130.973 us; speedup vs baseline: 1.2156x; 1.2156x over previous
//
#include <hip/hip_runtime.h>

// ---------------------------------------------------------------------------
// GCN 2-layer: out = A_norm * relu(A_norm*(X@W1)+b1) @ W2 + b2
// A_norm = D^-1/2 (A + I) D^-1/2.
//
// Round-12: REVERT to the measured-best round-10 configuration (131.0 us).
// (r11's early per-edge global deg atomics: 159us, reverted — random global
// atomic writes cost ~30us; keep per-edge randomness to reads + LDS.)
//   CSR: memset + rhist(+weight prep) + {rscatter || gemm1} + bsort(+dinv)
//   hs  = bf16( X@W1 )  UNSCALED      [n][128]   [fused gemm1, MFMA]
//   h1  = relu(dinv[c]*(sum dinv[s]*hs[s] + dinv[c]*hs[c]) + b1)  [gather1]
//   ps2 = bf16( dinv * (h1@W2) )      [n][64]    [gemm2, MFMA]
//   out = dinv*(A.ps2)+b2  fp32       [n][64]    [gather2]
// ---------------------------------------------------------------------------

typedef float f32x4 __attribute__((ext_vector_type(4)));
typedef short bf16x8 __attribute__((ext_vector_type(8)));

#define EPB 4096   // edges per block in bucket pass 1

__device__ inline float bf2f(unsigned short u) {
    return __uint_as_float(((unsigned int)u) << 16);
}
__device__ inline unsigned short f2bf(float f) {
    unsigned int x = __float_as_uint(f);
    x = x + 0x7FFFu + ((x >> 16) & 1u);   // round-to-nearest-even
    return (unsigned short)(x >> 16);
}
__device__ inline float4 cvt4(ushort4 u) {
    return make_float4(bf2f(u.x), bf2f(u.y), bf2f(u.z), bf2f(u.w));
}
__device__ inline void fma4(float4& a, float4 v, float d) {
    a.x += v.x * d; a.y += v.y * d; a.z += v.z * d; a.w += v.w * d;
}

// Pass 1: per-(bucket,block) offsets via atomicAdd into bucket counters.
// Extra blocks (>= nbR) convert/transpose weights to bf16.
__global__ __launch_bounds__(256) void k_rhist(const int* __restrict__ col,
                                               int* __restrict__ bbase,
                                               int* __restrict__ bucket_cnt,
                                               const float* __restrict__ W1,
                                               const float* __restrict__ W2,
                                               unsigned short* __restrict__ Wt1,
                                               unsigned short* __restrict__ Wt2,
                                               int e, int nbR, int nbB) {
    if ((int)blockIdx.x >= nbR) {
        int i = ((int)blockIdx.x - nbR) * 256 + threadIdx.x;
        if (i < 16384) {                       // W1: 128x128
            int k = i >> 7, nc = i & 127;
            Wt1[nc * 128 + k] = f2bf(W1[i]);
        } else if (i < 24576) {                // W2: 128x64
            int i2 = i - 16384;
            int k = i2 >> 6, nc = i2 & 63;
            Wt2[nc * 128 + k] = f2bf(W2[i2]);
        }
        return;
    }
    __shared__ int h[256];
    int t = threadIdx.x;
    h[t] = 0;
    __syncthreads();
    int base = blockIdx.x * EPB;
#pragma unroll
    for (int i = 0; i < EPB / 256; ++i) {
        int idx = base + t + i * 256;
        if (idx < e) atomicAdd(&h[col[idx] >> 8], 1);
    }
    __syncthreads();
    if (t < nbB) bbase[t * nbR + blockIdx.x] = atomicAdd(&bucket_cnt[t], h[t]);
}

// FUSED dispatch: blocks [0,nbR) = bucket scatter; blocks [nbR,nbR+nbg) =
// gemm1 (hs = bf16(X@W1), unscaled). The two halves are independent.
__global__ __launch_bounds__(256, 2) void k_fused(const int* __restrict__ row,
                                                  const int* __restrict__ col,
                                                  const int* __restrict__ bucket_cnt,
                                                  const int* __restrict__ bbase,
                                                  unsigned int* __restrict__ tmp,
                                                  const float* __restrict__ x,
                                                  const unsigned short* __restrict__ Wt,
                                                  unsigned short* __restrict__ hs,
                                                  int e, int n, int nbR, int nbB) {
    __shared__ int sbase[256];
    __shared__ int sh[256];
    __shared__ unsigned short Xs[128 * 136];
    __shared__ unsigned short Ws[128 * 136];
    int t = threadIdx.x;

    if ((int)blockIdx.x < nbR) {
        // ---- bucket scatter (tmp entry: (col&255)<<16 | row) ----
        int v = (t < nbB) ? bucket_cnt[t] : 0;
        sbase[t] = v;
        __syncthreads();
#pragma unroll
        for (int off = 1; off < 256; off <<= 1) {
            int u = (t >= off) ? sbase[t - off] : 0;
            __syncthreads();
            sbase[t] += u;
            __syncthreads();
        }
        int excl = sbase[t] - v;
        sbase[t] = excl + ((t < nbB) ? bbase[t * nbR + blockIdx.x] : 0);
        sh[t] = 0;
        __syncthreads();
        int b0 = blockIdx.x * EPB;
#pragma unroll
        for (int i = 0; i < EPB / 256; ++i) {
            int idx = b0 + t + i * 256;
            if (idx < e) {
                int c = col[idx];
                int bin = c >> 8;
                int rk = atomicAdd(&sh[bin], 1);
                tmp[sbase[bin] + rk] =
                    ((unsigned int)(c & 255) << 16) | (unsigned int)row[idx];
            }
        }
        return;
    }

    // ---- gemm1: tile 128x128, K=128, MFMA 16x16x32 ----
    int r0blk = ((int)blockIdx.x - nbR) * 128;

#pragma unroll
    for (int i = 0; i < 8; ++i) {
        int c = t + i * 256;
        int nc = c >> 4;
        int k0 = (c & 15) * 8;
        bf16x8 v = *(const bf16x8*)&Wt[nc * 128 + k0];
        *(bf16x8*)&Ws[nc * 136 + k0] = v;
    }
#pragma unroll
    for (int i = 0; i < 16; ++i) {
        int c = t + i * 256;
        int r = c >> 5;
        int kq = c & 31;
        float4 v = make_float4(0.f, 0.f, 0.f, 0.f);
        int gr = r0blk + r;
        if (gr < n) v = ((const float4*)x)[gr * 32 + kq];
        ushort4 o;
        o.x = f2bf(v.x); o.y = f2bf(v.y); o.z = f2bf(v.z); o.w = f2bf(v.w);
        *(ushort4*)&Xs[r * 136 + kq * 4] = o;
    }
    __syncthreads();

    int lane = t & 63, wave = t >> 6;
    int lrow = lane & 15;
    int lk = (lane >> 4) * 8;

    f32x4 acc[2][8];
#pragma unroll
    for (int mi = 0; mi < 2; ++mi)
#pragma unroll
        for (int ni = 0; ni < 8; ++ni) acc[mi][ni] = (f32x4){0.f, 0.f, 0.f, 0.f};

#pragma unroll
    for (int ks = 0; ks < 4; ++ks) {
        int kk = ks * 32 + lk;
        bf16x8 a0 = *(bf16x8*)&Xs[(wave * 32 + lrow) * 136 + kk];
        bf16x8 a1 = *(bf16x8*)&Xs[(wave * 32 + 16 + lrow) * 136 + kk];
#pragma unroll
        for (int ni = 0; ni < 8; ++ni) {
            bf16x8 b = *(bf16x8*)&Ws[(ni * 16 + lrow) * 136 + kk];
            acc[0][ni] = __builtin_amdgcn_mfma_f32_16x16x32_bf16(a0, b, acc[0][ni], 0, 0, 0);
            acc[1][ni] = __builtin_amdgcn_mfma_f32_16x16x32_bf16(a1, b, acc[1][ni], 0, 0, 0);
        }
    }

    int rq = (lane >> 4) * 4;
#pragma unroll
    for (int mi = 0; mi < 2; ++mi)
#pragma unroll
        for (int r = 0; r < 4; ++r) {
            int lrw = wave * 32 + mi * 16 + rq + r;
            int grow = r0blk + lrw;
            if (grow < n) {
#pragma unroll
                for (int ni = 0; ni < 8; ++ni)
                    hs[grow * 128 + ni * 16 + lrow] = f2bf(acc[mi][ni][r]);
            }
        }
}

// Pass 2: per-bucket counting sort; emits indptr, dinv, srcidx. Bucket range
// re-derived locally from bucket_cnt.
__global__ __launch_bounds__(256) void k_bsort(const unsigned int* __restrict__ tmp,
                                               const int* __restrict__ bucket_cnt,
                                               int* __restrict__ indptr,
                                               float* __restrict__ dinv,
                                               unsigned short* __restrict__ srcidx,
                                               int n, int e, int nbB) {
    __shared__ int cnt[256];
    __shared__ int pre[256];
    int b = blockIdx.x;
    int t = threadIdx.x;

    int v = (t < nbB) ? bucket_cnt[t] : 0;
    pre[t] = v;
    __syncthreads();
#pragma unroll
    for (int off = 1; off < 256; off <<= 1) {
        int u = (t >= off) ? pre[t - off] : 0;
        __syncthreads();
        pre[t] += u;
        __syncthreads();
    }
    int beg = pre[b] - ((b < nbB) ? bucket_cnt[b] : 0);
    int end = pre[b];
    __syncthreads();

    cnt[t] = 0;
    __syncthreads();
    for (int i = beg + t; i < end; i += 256) atomicAdd(&cnt[tmp[i] >> 16], 1);
    __syncthreads();
    v = cnt[t];
    pre[t] = v;
    __syncthreads();
#pragma unroll
    for (int off = 1; off < 256; off <<= 1) {
        int u = (t >= off) ? pre[t - off] : 0;
        __syncthreads();
        pre[t] += u;
        __syncthreads();
    }
    int myexcl = pre[t] - v;
    int node = b * 256 + t;
    if (node < n) {
        indptr[node] = beg + myexcl;
        dinv[node] = rsqrtf((float)v + 1.0f);
    }
    if (b == nbB - 1 && t == 0) indptr[n] = e;
    __syncthreads();
    pre[t] = beg + myexcl;
    cnt[t] = 0;
    __syncthreads();
    for (int i = beg + t; i < end; i += 256) {
        unsigned int u = tmp[i];
        int cl = u >> 16;
        int rk = atomicAdd(&cnt[cl], 1);
        srcidx[pre[cl] + rk] = (unsigned short)(u & 0xFFFFu);
    }
}

// Gather1: one wave per node; contiguous half-runs, 8 gathers in flight.
// Deferred norm: accumulate dinv[src]*hs_raw[src]; epilogue *dinv[col].
__global__ __launch_bounds__(256) void k_gather1(const int* __restrict__ indptr,
                                                 const unsigned short* __restrict__ srcidx,
                                                 const unsigned short* __restrict__ hs,
                                                 const float* __restrict__ dinv,
                                                 const float* __restrict__ b1,
                                                 unsigned short* __restrict__ h1, int n) {
    int wid = (blockIdx.x * 256 + threadIdx.x) >> 6;
    if (wid >= n) return;
    int lane = threadIdx.x & 63;
    int half = lane >> 5;
    int hl = lane & 31;
    const ushort4* hv = (const ushort4*)hs;   // row stride 32 ushort4

    int beg = indptr[wid], end = indptr[wid + 1];
    int c0 = (end - beg + 1) >> 1;
    int j    = beg + half * c0;
    int jend = half ? end : (beg + c0);

    float4 a0 = make_float4(0.f, 0.f, 0.f, 0.f), a1 = a0, a2 = a0, a3 = a0;

    for (; j + 7 < jend; j += 8) {
        int s0 = srcidx[j],     s1 = srcidx[j + 1];
        int s2 = srcidx[j + 2], s3 = srcidx[j + 3];
        int s4 = srcidx[j + 4], s5 = srcidx[j + 5];
        int s6 = srcidx[j + 6], s7 = srcidx[j + 7];
        float d0 = dinv[s0], d1 = dinv[s1], d2 = dinv[s2], d3 = dinv[s3];
        float d4 = dinv[s4], d5 = dinv[s5], d6 = dinv[s6], d7 = dinv[s7];
        float4 v0 = cvt4(hv[s0 * 32 + hl]);
        float4 v1 = cvt4(hv[s1 * 32 + hl]);
        float4 v2 = cvt4(hv[s2 * 32 + hl]);
        float4 v3 = cvt4(hv[s3 * 32 + hl]);
        float4 v4 = cvt4(hv[s4 * 32 + hl]);
        float4 v5 = cvt4(hv[s5 * 32 + hl]);
        float4 v6 = cvt4(hv[s6 * 32 + hl]);
        float4 v7 = cvt4(hv[s7 * 32 + hl]);
        fma4(a0, v0, d0); fma4(a1, v1, d1); fma4(a2, v2, d2); fma4(a3, v3, d3);
        fma4(a0, v4, d4); fma4(a1, v5, d5); fma4(a2, v6, d6); fma4(a3, v7, d7);
    }
    if (j + 3 < jend) {
        int s0 = srcidx[j], s1 = srcidx[j + 1], s2 = srcidx[j + 2], s3 = srcidx[j + 3];
        fma4(a0, cvt4(hv[s0 * 32 + hl]), dinv[s0]);
        fma4(a1, cvt4(hv[s1 * 32 + hl]), dinv[s1]);
        fma4(a2, cvt4(hv[s2 * 32 + hl]), dinv[s2]);
        fma4(a3, cvt4(hv[s3 * 32 + hl]), dinv[s3]);
        j += 4;
    }
    for (; j < jend; ++j) {
        int s0 = srcidx[j];
        fma4(a0, cvt4(hv[s0 * 32 + hl]), dinv[s0]);
    }

    float dw = dinv[wid];
    if (half == 0) fma4(a1, cvt4(hv[wid * 32 + hl]), dw);   // self-loop once

    float4 tsum;
    tsum.x = a0.x + a1.x + a2.x + a3.x;
    tsum.y = a0.y + a1.y + a2.y + a3.y;
    tsum.z = a0.z + a1.z + a2.z + a3.z;
    tsum.w = a0.w + a1.w + a2.w + a3.w;
    tsum.x += __shfl_xor(tsum.x, 32);
    tsum.y += __shfl_xor(tsum.y, 32);
    tsum.z += __shfl_xor(tsum.z, 32);
    tsum.w += __shfl_xor(tsum.w, 32);

    if (half == 0) {
        float4 bb = *(const float4*)&b1[hl * 4];
        ushort4 o;
        o.x = f2bf(fmaxf(tsum.x * dw + bb.x, 0.f));
        o.y = f2bf(fmaxf(tsum.y * dw + bb.y, 0.f));
        o.z = f2bf(fmaxf(tsum.z * dw + bb.z, 0.f));
        o.w = f2bf(fmaxf(tsum.w * dw + bb.w, 0.f));
        ((ushort4*)h1)[wid * 32 + hl] = o;
    }
}

// GEMM2 (MFMA): ps2 = bf16( dinv[i] * (h1 @ W2) ). Tile 128x64, K=128.
__global__ __launch_bounds__(256, 3) void k_gemm2(const unsigned short* __restrict__ h1,
                                                  const unsigned short* __restrict__ Wt,
                                                  const float* __restrict__ dinv,
                                                  unsigned short* __restrict__ ps2, int n) {
    __shared__ unsigned short Xs[128 * 136];
    __shared__ unsigned short Ws[64 * 136];
    __shared__ float dinv_s[128];
    int t = threadIdx.x;
    int r0blk = blockIdx.x * 128;

#pragma unroll
    for (int i = 0; i < 4; ++i) {
        int c = t + i * 256;
        int nc = c >> 4;
        int k0 = (c & 15) * 8;
        bf16x8 v = *(const bf16x8*)&Wt[nc * 128 + k0];
        *(bf16x8*)&Ws[nc * 136 + k0] = v;
    }
#pragma unroll
    for (int i = 0; i < 8; ++i) {
        int c = t + i * 256;
        int r = c >> 4;
        int k0 = (c & 15) * 8;
        int gr = r0blk + r;
        bf16x8 v = (bf16x8)(short)0;
        if (gr < n) v = *(const bf16x8*)&h1[gr * 128 + k0];
        *(bf16x8*)&Xs[r * 136 + k0] = v;
    }
    if (t < 128) {
        int gr = r0blk + t;
        dinv_s[t] = (gr < n) ? dinv[gr] : 0.f;
    }
    __syncthreads();

    int lane = t & 63, wave = t >> 6;
    int lrow = lane & 15;
    int lk = (lane >> 4) * 8;

    f32x4 acc[2][4];
#pragma unroll
    for (int mi = 0; mi < 2; ++mi)
#pragma unroll
        for (int ni = 0; ni < 4; ++ni) acc[mi][ni] = (f32x4){0.f, 0.f, 0.f, 0.f};

#pragma unroll
    for (int ks = 0; ks < 4; ++ks) {
        int kk = ks * 32 + lk;
        bf16x8 a0 = *(bf16x8*)&Xs[(wave * 32 + lrow) * 136 + kk];
        bf16x8 a1 = *(bf16x8*)&Xs[(wave * 32 + 16 + lrow) * 136 + kk];
#pragma unroll
        for (int ni = 0; ni < 4; ++ni) {
            bf16x8 b = *(bf16x8*)&Ws[(ni * 16 + lrow) * 136 + kk];
            acc[0][ni] = __builtin_amdgcn_mfma_f32_16x16x32_bf16(a0, b, acc[0][ni], 0, 0, 0);
            acc[1][ni] = __builtin_amdgcn_mfma_f32_16x16x32_bf16(a1, b, acc[1][ni], 0, 0, 0);
        }
    }

    int rq = (lane >> 4) * 4;
#pragma unroll
    for (int mi = 0; mi < 2; ++mi)
#pragma unroll
        for (int r = 0; r < 4; ++r) {
            int lrw = wave * 32 + mi * 16 + rq + r;
            int grow = r0blk + lrw;
            if (grow < n) {
                float dv = dinv_s[lrw];
#pragma unroll
                for (int ni = 0; ni < 4; ++ni)
                    ps2[grow * 64 + ni * 16 + lrow] = f2bf(acc[mi][ni][r] * dv);
            }
        }
}

// Gather2: one wave per node; contiguous half-runs, 8 in flight, uint/lane.
__global__ __launch_bounds__(256) void k_gather2(const int* __restrict__ indptr,
                                                 const unsigned short* __restrict__ srcidx,
                                                 const unsigned short* __restrict__ ps2,
                                                 const float* __restrict__ dinv,
                                                 const float* __restrict__ b2,
                                                 float* __restrict__ out, int n) {
    int wid = (blockIdx.x * 256 + threadIdx.x) >> 6;
    if (wid >= n) return;
    int lane = threadIdx.x & 63;
    int half = lane >> 5;
    int hl = lane & 31;
    const unsigned int* pv = (const unsigned int*)ps2;   // row stride 32 uints

    int beg = indptr[wid], end = indptr[wid + 1];
    int c0 = (end - beg + 1) >> 1;
    int j    = beg + half * c0;
    int jend = half ? end : (beg + c0);

    float2 a0 = make_float2(0.f, 0.f), a1 = a0, a2 = a0, a3 = a0;

    for (; j + 7 < jend; j += 8) {
        int s0 = srcidx[j],     s1 = srcidx[j + 1];
        int s2 = srcidx[j + 2], s3 = srcidx[j + 3];
        int s4 = srcidx[j + 4], s5 = srcidx[j + 5];
        int s6 = srcidx[j + 6], s7 = srcidx[j + 7];
        unsigned int u0 = pv[s0 * 32 + hl];
        unsigned int u1 = pv[s1 * 32 + hl];
        unsigned int u2 = pv[s2 * 32 + hl];
        unsigned int u3 = pv[s3 * 32 + hl];
        unsigned int u4 = pv[s4 * 32 + hl];
        unsigned int u5 = pv[s5 * 32 + hl];
        unsigned int u6 = pv[s6 * 32 + hl];
        unsigned int u7 = pv[s7 * 32 + hl];
        a0.x += bf2f((unsigned short)u0); a0.y += bf2f((unsigned short)(u0 >> 16));
        a1.x += bf2f((unsigned short)u1); a1.y += bf2f((unsigned short)(u1 >> 16));
        a2.x += bf2f((unsigned short)u2); a2.y += bf2f((unsigned short)(u2 >> 16));
        a3.x += bf2f((unsigned short)u3); a3.y += bf2f((unsigned short)(u3 >> 16));
        a0.x += bf2f((unsigned short)u4); a0.y += bf2f((unsigned short)(u4 >> 16));
        a1.x += bf2f((unsigned short)u5); a1.y += bf2f((unsigned short)(u5 >> 16));
        a2.x += bf2f((unsigned short)u6); a2.y += bf2f((unsigned short)(u6 >> 16));
        a3.x += bf2f((unsigned short)u7); a3.y += bf2f((unsigned short)(u7 >> 16));
    }
    if (j + 3 < jend) {
        int s0 = srcidx[j], s1 = srcidx[j + 1], s2 = srcidx[j + 2], s3 = srcidx[j + 3];
        unsigned int u0 = pv[s0 * 32 + hl];
        unsigned int u1 = pv[s1 * 32 + hl];
        unsigned int u2 = pv[s2 * 32 + hl];
        unsigned int u3 = pv[s3 * 32 + hl];
        a0.x += bf2f((unsigned short)u0); a0.y += bf2f((unsigned short)(u0 >> 16));
        a1.x += bf2f((unsigned short)u1); a1.y += bf2f((unsigned short)(u1 >> 16));
        a2.x += bf2f((unsigned short)u2); a2.y += bf2f((unsigned short)(u2 >> 16));
        a3.x += bf2f((unsigned short)u3); a3.y += bf2f((unsigned short)(u3 >> 16));
        j += 4;
    }
    for (; j < jend; ++j) {
        unsigned int u = pv[srcidx[j] * 32 + hl];
        a0.x += bf2f((unsigned short)u); a0.y += bf2f((unsigned short)(u >> 16));
    }

    if (half == 0) {   // self-loop once
        unsigned int u = pv[wid * 32 + hl];
        a1.x += bf2f((unsigned short)u); a1.y += bf2f((unsigned short)(u >> 16));
    }

    float2 tsum;
    tsum.x = a0.x + a1.x + a2.x + a3.x;
    tsum.y = a0.y + a1.y + a2.y + a3.y;
    tsum.x += __shfl_xor(tsum.x, 32);
    tsum.y += __shfl_xor(tsum.y, 32);

    if (half == 0) {
        float d = dinv[wid];
        float2 bb = *(const float2*)&b2[hl * 2];
        float2 o;
        o.x = tsum.x * d + bb.x;
        o.y = tsum.y * d + bb.y;
        ((float2*)out)[wid * 32 + hl] = o;
    }
}

extern "C" void kernel_launch(void* const* d_in, const int* in_sizes, int n_in,
                              void* d_out, int out_size, void* d_ws, size_t ws_size,
                              hipStream_t stream) {
    const float* x  = (const float*)d_in[0];
    const int*   ei = (const int*)d_in[1];
    const float* W1 = (const float*)d_in[2];
    const float* b1 = (const float*)d_in[3];
    const float* W2 = (const float*)d_in[4];
    const float* b2 = (const float*)d_in[5];
    float* out = (float*)d_out;

    int n = in_sizes[0] / 128;       // 50000
    int e = in_sizes[1] / 2;         // 800000
    const int* row = ei;             // sources
    const int* col = ei + e;         // destinations

    int nbR = (e + EPB - 1) / EPB;   // 196 pass-1 blocks
    int nbB = (n + 255) / 256;       // 196 buckets
    int m   = nbB * nbR;             // 38416 per-(bucket,block) offsets
    int nbg = (n + 127) / 128;       // 391 gemm blocks

    // Workspace layout (int units; 16B-aligned sections).
    int* iw = (int*)d_ws;
    size_t o = 0;
    int* bucket_cnt  = iw + o; o += 256;
    int* bbase       = iw + o; o += (size_t)m;           o = (o + 3) & ~(size_t)3;
    int* indptr      = iw + o; o += (size_t)(n + 1);     o = (o + 3) & ~(size_t)3;
    float* dinv      = (float*)(iw + o); o += (size_t)n; o = (o + 3) & ~(size_t)3;
    unsigned int* tmp = (unsigned int*)(iw + o); o += (size_t)e; o = (o + 3) & ~(size_t)3;
    unsigned short* srcidx = (unsigned short*)(iw + o); o += (size_t)(e / 2 + 2); o = (o + 3) & ~(size_t)3;
    unsigned short* Wt1 = (unsigned short*)(iw + o); o += 8192;
    unsigned short* Wt2 = (unsigned short*)(iw + o); o += 4096;
    unsigned short* hs  = (unsigned short*)(iw + o);     // [n][128] bf16 (unscaled)
    unsigned short* h1  = hs + (size_t)n * 128;          // [n][128] bf16
    unsigned short* ps2 = hs;                            // reuse: [n][64]

    hipMemsetAsync(bucket_cnt, 0, 256 * sizeof(int), stream);
    k_rhist<<<nbR + 96, 256, 0, stream>>>(col, bbase, bucket_cnt, W1, W2, Wt1, Wt2, e, nbR, nbB);
    k_fused<<<nbR + nbg, 256, 0, stream>>>(row, col, bucket_cnt, bbase, tmp, x, Wt1, hs, e, n, nbR, nbB);
    k_bsort<<<nbB, 256, 0, stream>>>(tmp, bucket_cnt, indptr, dinv, srcidx, n, e, nbB);

    k_gather1<<<(n * 64 + 255) / 256, 256, 0, stream>>>(indptr, srcidx, hs, dinv, b1, h1, n);
    k_gemm2<<<nbg, 256, 0, stream>>>(h1, Wt2, dinv, ps2, n);
    k_gather2<<<(n * 64 + 255) / 256, 256, 0, stream>>>(indptr, srcidx, ps2, dinv, b2, out, n);
}